// Round 5
// baseline (340.077 us; speedup 1.0000x reference)
//
#include <hip/hip_runtime.h>
#include <hip/hip_bf16.h>

#define N_NODES 100000
#define N_EDGES 1600000
#define NFEAT 128
#define PCD 32
#define KCH 4

#define TILE_E 4096
#define T_TILES 391            // ceil(N_EDGES / TILE_E)
#define BSH 8
#define NB 391                 // ceil(N_NODES / 256)
#define CAP 5120               // per-bucket capacity (mean 4096, +16 sigma)
#define NCAP (NB * CAP)        // 2,001,920

// ---------------- workspace layout (bytes) ----------------
#define WS_WALL    0           // Wall [128*128] f32 -> 65,536
#define WS_CBIAS   65536       // cbias [128] f32 -> 66,048
#define WS_P       66048       // p [N*8] f32 -> 3,266,048
#define WS_C       3266048     // c [N*128] bf16 -> 28,866,048
#define WS_RS      28866048    // row_start [N] i32 -> 29,266,048
#define WS_RE      29266048    // row_end [N] i32 -> 29,666,048
#define WS_CUR     29666048    // gcursor [NB] i32 -> 29,667,840 (padded)
#define WS_BUCK    29667840    // bucketed [NCAP] uint2 -> 45,683,200
#define WS_CSRCOL  45683200    // csr_col [NCAP] i32 -> 53,690,880
#define WS_CSRW    53690880    // csr_w [NCAP*2] u32 -> 69,706,240

static __device__ __forceinline__ unsigned short f2bf(float f) {
    union { float f; unsigned int u; } v; v.f = f;
    unsigned int u = v.u;
    return (unsigned short)((u + 0x7fffu + ((u >> 16) & 1u)) >> 16);  // RNE
}

// ---- fuse Wlin@Wconv -> Wall; cbias = blin@Wconv; init gcursor[b]=b*CAP ----
__global__ void k_fuse(const float* __restrict__ Wlin, const float* __restrict__ Wconv,
                       const float* __restrict__ blin, float* __restrict__ Wall,
                       float* __restrict__ cbias, int* __restrict__ gcursor) {
    int tid = blockIdx.x * 256 + threadIdx.x;
    if (tid < 16384) {
        int k = tid >> 12;
        int rem = tid & 4095;
        int f = rem >> 5;
        int q = rem & 31;
        float a = 0.f;
        for (int pp = 0; pp < 32; pp++)
            a += Wlin[(k * 128 + f) * 32 + pp] * Wconv[(k * 32 + pp) * 32 + q];
        Wall[f * 128 + k * 32 + q] = a;
    } else if (tid < 16512) {
        int i = tid - 16384;
        int k = i >> 5;
        int q = i & 31;
        float a = 0.f;
        for (int pp = 0; pp < 32; pp++)
            a += blin[k * 32 + pp] * Wconv[(k * 32 + pp) * 32 + q];
        cbias[k * 32 + q] = a;
    } else if (tid - 16512 < NB) {
        gcursor[tid - 16512] = (tid - 16512) * CAP;
    }
}

// ---- c[N,128] = bf16(x @ Wall + cbias)  AND  p[N,8] = x @ [aW1_lo | aW1_hi] ----
#define XS_LD 132
__global__ __launch_bounds__(256) void k_cgemm(const float* __restrict__ x,
                                               const float* __restrict__ Wall,
                                               const float* __restrict__ cbias,
                                               const float* __restrict__ aW1,
                                               unsigned short* __restrict__ c,
                                               float* __restrict__ p) {
    __shared__ float xs[64 * XS_LD];
    __shared__ float aT[8 * XS_LD];
    int t = threadIdx.x;
    int row0 = blockIdx.x * 64;

    for (int i = t; i < 1024; i += 256) {
        int j = i >> 7;
        int f = i & 127;
        float v = (j < 4) ? aW1[f * 4 + j] : aW1[512 + f * 4 + (j - 4)];
        aT[j * XS_LD + f] = v;
    }

    const float4* xg = (const float4*)(x + (size_t)row0 * 128);
    for (int i = 0; i < 8; i++) {
        int idx = i * 256 + t;
        int r = idx >> 5;
        int cc = idx & 31;
        float4 v = make_float4(0.f, 0.f, 0.f, 0.f);
        if (row0 + r < N_NODES) v = xg[idx];
        *(float4*)(xs + r * XS_LD + cc * 4) = v;
    }
    __syncthreads();

    int c0 = (t & 31) * 4;
    int r0 = (t >> 5) * 8;
    float acc[8][4] = {};

    for (int f4 = 0; f4 < 32; f4++) {
        float4 wf0 = *(const float4*)(Wall + (f4 * 4 + 0) * 128 + c0);
        float4 wf1 = *(const float4*)(Wall + (f4 * 4 + 1) * 128 + c0);
        float4 wf2 = *(const float4*)(Wall + (f4 * 4 + 2) * 128 + c0);
        float4 wf3 = *(const float4*)(Wall + (f4 * 4 + 3) * 128 + c0);
        for (int r = 0; r < 8; r++) {
            float4 xv = *(const float4*)(xs + (r0 + r) * XS_LD + f4 * 4);
            acc[r][0] += xv.x * wf0.x + xv.y * wf1.x + xv.z * wf2.x + xv.w * wf3.x;
            acc[r][1] += xv.x * wf0.y + xv.y * wf1.y + xv.z * wf2.y + xv.w * wf3.y;
            acc[r][2] += xv.x * wf0.z + xv.y * wf1.z + xv.z * wf2.z + xv.w * wf3.z;
            acc[r][3] += xv.x * wf0.w + xv.y * wf1.w + xv.z * wf2.w + xv.w * wf3.w;
        }
    }

    float4 cb = *(const float4*)(cbias + c0);
    for (int r = 0; r < 8; r++) {
        int row = row0 + r0 + r;
        if (row < N_NODES) {
            ushort4 o;
            o.x = f2bf(acc[r][0] + cb.x);
            o.y = f2bf(acc[r][1] + cb.y);
            o.z = f2bf(acc[r][2] + cb.z);
            o.w = f2bf(acc[r][3] + cb.w);
            *(ushort4*)(c + (size_t)row * 128 + c0) = o;
        }
    }

    int j = t & 7;
    const float* arow = aT + j * XS_LD;
    for (int pass = 0; pass < 2; pass++) {
        int r = (t >> 3) + pass * 32;
        const float* xrow = xs + r * XS_LD;
        float accp = 0.f;
        for (int f4 = 0; f4 < 32; f4++) {
            float4 xv = *(const float4*)(xrow + f4 * 4);
            float4 av = *(const float4*)(arow + f4 * 4);
            accp += xv.x * av.x + xv.y * av.y + xv.z * av.z + xv.w * av.w;
        }
        int row = row0 + r;
        if (row < N_NODES) p[(size_t)row * 8 + j] = accp;
    }
}

// ---- bucket scatter: LDS-reorder tile by bucket, claim global runs, coalesced out ----
__global__ __launch_bounds__(256) void k_bucket_scatter(const int* __restrict__ erow,
                                                        const int* __restrict__ ecol,
                                                        int* __restrict__ gcursor,
                                                        uint2* __restrict__ bucketed) {
    __shared__ int lcnt[NB];
    __shared__ int lstart[NB];
    __shared__ int lcur[NB];
    __shared__ int gbase[NB];
    __shared__ uint2 buf[TILE_E];
    int t = threadIdx.x;
    int tile = blockIdx.x;
    int base = tile * TILE_E;
    int cnt = N_EDGES - base; if (cnt > TILE_E) cnt = TILE_E;

    for (int i = t; i < NB; i += 256) lcnt[i] = 0;
    __syncthreads();

    int rows[TILE_E / 256], cols[TILE_E / 256];
    #pragma unroll
    for (int i = 0; i < TILE_E / 256; i++) {
        int e = base + i * 256 + t;
        if (e < N_EDGES) {
            rows[i] = erow[e];
            cols[i] = ecol[e];
            atomicAdd(&lcnt[rows[i] >> BSH], 1);
        } else rows[i] = -1;
    }
    __syncthreads();

    if (t < 64) {
        // wave 0: exclusive scan of lcnt -> lstart, lcur
        int carry = 0;
        for (int ck = 0; ck < (NB + 63) / 64; ck++) {
            int i = ck * 64 + t;
            int v = (i < NB) ? lcnt[i] : 0;
            int s = v;
            #pragma unroll
            for (int d = 1; d < 64; d <<= 1) {
                int u = __shfl_up(s, d);
                if (t >= d) s += u;
            }
            int excl = s - v + carry;
            if (i < NB) { lstart[i] = excl; lcur[i] = excl; }
            carry += __shfl(s, 63);
        }
    } else {
        // waves 1-3: claim global runs (overlapped with scan)
        for (int i = t - 64; i < NB; i += 192)
            gbase[i] = atomicAdd(&gcursor[i], lcnt[i]);
    }
    __syncthreads();

    #pragma unroll
    for (int i = 0; i < TILE_E / 256; i++) {
        if (rows[i] >= 0) {
            int b = rows[i] >> BSH;
            int pos = atomicAdd(&lcur[b], 1);
            buf[pos] = make_uint2((unsigned)rows[i], (unsigned)cols[i]);
        }
    }
    __syncthreads();

    for (int jj = t; jj < cnt; jj += 256) {
        uint2 pr = buf[jj];
        int b = (int)pr.x >> BSH;
        int gpos = gbase[b] + (jj - lstart[b]);
        bucketed[gpos] = pr;
    }
}

// ---- per-bucket: CSR row offsets + softmax + fine scatter (L2-local) ----
__global__ __launch_bounds__(256) void k_edge_compute(const uint2* __restrict__ bucketed,
                                                      const int* __restrict__ gcursor,
                                                      const float* __restrict__ p,
                                                      const float* __restrict__ aW2,
                                                      const float* __restrict__ ab1,
                                                      const float* __restrict__ ab2,
                                                      int* __restrict__ row_start,
                                                      int* __restrict__ row_end,
                                                      int* __restrict__ csr_col,
                                                      unsigned int* __restrict__ csr_w) {
    __shared__ int rcur[256];
    __shared__ int wtot[4];
    int b = blockIdx.x;
    int t = threadIdx.x;
    int bstart = b * CAP;
    int bend = gcursor[b];      // end cursor after all claims
    int row0 = b << BSH;
    int nrows = N_NODES - row0; if (nrows > 256) nrows = 256;

    rcur[t] = 0;
    __syncthreads();
    for (int i = bstart + t; i < bend; i += 256)
        atomicAdd(&rcur[(int)bucketed[i].x - row0], 1);
    __syncthreads();
    int v = rcur[t];
    int s = v;
    #pragma unroll
    for (int d = 1; d < 64; d <<= 1) {
        int u = __shfl_up(s, d);
        if ((t & 63) >= d) s += u;
    }
    if ((t & 63) == 63) wtot[t >> 6] = s;
    __syncthreads();
    int add = 0;
    for (int w = 0; w < (t >> 6); w++) add += wtot[w];
    int pos0 = bstart + (s - v + add);
    __syncthreads();
    rcur[t] = pos0;
    if (t < nrows) {
        row_start[row0 + t] = pos0;
        row_end[row0 + t] = pos0 + v;
    }
    __syncthreads();

    for (int i = bstart + t; i < bend; i += 256) {
        uint2 pr = bucketed[i];
        int r = (int)pr.x;
        int cl = (int)pr.y;
        float4 pc = *(const float4*)(p + (size_t)cl * 8);
        float4 prr = *(const float4*)(p + (size_t)r * 8 + 4);
        float h0 = pc.x + prr.x + ab1[0];
        float h1 = pc.y + prr.y + ab1[1];
        float h2 = pc.z + prr.z + ab1[2];
        float h3 = pc.w + prr.w + ab1[3];
        float sc[4];
        #pragma unroll
        for (int jq = 0; jq < 4; jq++)
            sc[jq] = h0 * aW2[jq] + h1 * aW2[4 + jq] + h2 * aW2[8 + jq] + h3 * aW2[12 + jq] + ab2[jq];
        float m = fmaxf(fmaxf(sc[0], sc[1]), fmaxf(sc[2], sc[3]));
        float e0 = expf(sc[0] - m), e1 = expf(sc[1] - m), e2 = expf(sc[2] - m), e3 = expf(sc[3] - m);
        float inv = 1.f / (e0 + e1 + e2 + e3);
        unsigned int w01 = (unsigned int)f2bf(e0 * inv) | ((unsigned int)f2bf(e1 * inv) << 16);
        unsigned int w23 = (unsigned int)f2bf(e2 * inv) | ((unsigned int)f2bf(e3 * inv) << 16);
        int pos = atomicAdd(&rcur[r - row0], 1);
        csr_col[pos] = cl;
        uint2 wp; wp.x = w01; wp.y = w23;
        *(uint2*)(csr_w + (size_t)pos * 2) = wp;
    }
}

// ---- aggregation (pull): persistent waves; bf16 c + bf16 w; norm + classifier ----
static __device__ __forceinline__ float bf_lo(unsigned int u) { return __uint_as_float(u << 16); }
static __device__ __forceinline__ float bf_hi(unsigned int u) { return __uint_as_float(u & 0xffff0000u); }

#define AGG_BLOCKS 1024
__global__ __launch_bounds__(256) void k_agg(const int* __restrict__ csr_col,
                                             const unsigned int* __restrict__ csr_w,
                                             const unsigned int* __restrict__ c4,
                                             const int* __restrict__ row_start,
                                             const int* __restrict__ row_end,
                                             const float* __restrict__ bch,
                                             const float* __restrict__ Wcls,
                                             const float* __restrict__ bcls,
                                             float* __restrict__ out) {
    int lane = threadIdx.x & 63;
    int wid0 = (blockIdx.x * 256 + threadIdx.x) >> 6;
    const int nwaves = AGG_BLOCKS * 4;
    int ch = lane >> 4;
    int pair = ch >> 1;
    int wshl = (ch & 1) ? 0 : 16;     // (wu << wshl) & 0xffff0000 = this channel's w
    int f0 = 2 * lane, f1 = 2 * lane + 1;
    float bch0 = bch[f0], bch1 = bch[f1];
    float wc0 = Wcls[f0], wc1 = Wcls[f1];

    for (int n = wid0; n < N_NODES; n += nwaves) {
        int start = row_start[n];
        int end = row_end[n];

        float acc0 = 0.f, acc1 = 0.f;
        int idx = start;
        for (; idx + 7 < end; idx += 8) {
            int col[8]; unsigned int wu[8], u[8];
            #pragma unroll
            for (int q = 0; q < 8; q++) {
                col[q] = csr_col[idx + q];
                wu[q] = csr_w[(size_t)(idx + q) * 2 + pair];
            }
            #pragma unroll
            for (int q = 0; q < 8; q++) u[q] = c4[(size_t)col[q] * 64 + lane];
            #pragma unroll
            for (int q = 0; q < 8; q++) {
                float w = __uint_as_float((wu[q] << wshl) & 0xffff0000u);
                acc0 += w * bf_lo(u[q]);
                acc1 += w * bf_hi(u[q]);
            }
        }
        for (; idx + 3 < end; idx += 4) {
            int col[4]; unsigned int wu[4], u[4];
            #pragma unroll
            for (int q = 0; q < 4; q++) {
                col[q] = csr_col[idx + q];
                wu[q] = csr_w[(size_t)(idx + q) * 2 + pair];
            }
            #pragma unroll
            for (int q = 0; q < 4; q++) u[q] = c4[(size_t)col[q] * 64 + lane];
            #pragma unroll
            for (int q = 0; q < 4; q++) {
                float w = __uint_as_float((wu[q] << wshl) & 0xffff0000u);
                acc0 += w * bf_lo(u[q]);
                acc1 += w * bf_hi(u[q]);
            }
        }
        for (; idx < end; idx++) {
            int col0 = csr_col[idx];
            unsigned int wu0 = csr_w[(size_t)idx * 2 + pair];
            unsigned int u0 = c4[(size_t)col0 * 64 + lane];
            float w = __uint_as_float((wu0 << wshl) & 0xffff0000u);
            acc0 += w * bf_lo(u0);
            acc1 += w * bf_hi(u0);
        }

        float v0 = acc0 + bch0;
        float v1 = acc1 + bch1;

        float ss = v0 * v0 + v1 * v1;
        #pragma unroll
        for (int m = 1; m <= 8; m <<= 1) ss += __shfl_xor(ss, m);
        float inv = 1.f / fmaxf(sqrtf(ss), 1e-12f);
        v0 *= inv;
        v1 *= inv;

        *(float2*)(out + (size_t)n * 128 + f0) = make_float2(v0, v1);

        float pl = v0 * wc0 + v1 * wc1;
        #pragma unroll
        for (int m = 1; m <= 32; m <<= 1) pl += __shfl_xor(pl, m);
        if (lane == 0) out[(size_t)N_NODES * 128 + n] = pl + bcls[0];
    }
}

extern "C" void kernel_launch(void* const* d_in, const int* in_sizes, int n_in,
                              void* d_out, int out_size, void* d_ws, size_t ws_size,
                              hipStream_t stream) {
    const float* x    = (const float*)d_in[0];
    const int*   erow = (const int*)d_in[1];
    const int*   ecol = (const int*)d_in[2];
    const float* aW1  = (const float*)d_in[3];
    const float* ab1  = (const float*)d_in[4];
    const float* aW2  = (const float*)d_in[5];
    const float* ab2  = (const float*)d_in[6];
    const float* Wlin = (const float*)d_in[7];
    const float* blin = (const float*)d_in[8];
    const float* Wconv= (const float*)d_in[9];
    const float* bch  = (const float*)d_in[10];
    const float* Wcls = (const float*)d_in[11];
    const float* bcls = (const float*)d_in[12];
    float* out = (float*)d_out;

    char* ws = (char*)d_ws;
    float*          Wall    = (float*)(ws + WS_WALL);
    float*          cbias   = (float*)(ws + WS_CBIAS);
    float*          p       = (float*)(ws + WS_P);
    unsigned short* c       = (unsigned short*)(ws + WS_C);
    int*            rstart  = (int*)(ws + WS_RS);
    int*            rend    = (int*)(ws + WS_RE);
    int*            gcursor = (int*)(ws + WS_CUR);
    uint2*          bucketed= (uint2*)(ws + WS_BUCK);
    int*            csr_col = (int*)(ws + WS_CSRCOL);
    unsigned int*   csr_w   = (unsigned int*)(ws + WS_CSRW);

    k_fuse<<<67, 256, 0, stream>>>(Wlin, Wconv, blin, Wall, cbias, gcursor);
    k_cgemm<<<(N_NODES + 63) / 64, 256, 0, stream>>>(x, Wall, cbias, aW1, c, p);
    k_bucket_scatter<<<T_TILES, 256, 0, stream>>>(erow, ecol, gcursor, bucketed);
    k_edge_compute<<<NB, 256, 0, stream>>>(bucketed, gcursor, p, aW2, ab1, ab2,
                                           rstart, rend, csr_col, csr_w);
    k_agg<<<AGG_BLOCKS, 256, 0, stream>>>(csr_col, csr_w, (const unsigned int*)c,
                                          rstart, rend, bch, Wcls, bcls, out);
}

// Round 6
// 321.381 us; speedup vs baseline: 1.0582x; 1.0582x over previous
//
#include <hip/hip_runtime.h>
#include <hip/hip_bf16.h>

#define N_NODES 100000
#define N_EDGES 1600000
#define NFEAT 128
#define PCD 32
#define KCH 4

#define TILE_E 4096
#define T_TILES 391            // ceil(N_EDGES / TILE_E)
#define BSH 8
#define NB 391                 // ceil(N_NODES / 256)
#define CAP 5120               // per-bucket capacity (mean 4096, +16 sigma)
#define NCAP (NB * CAP)        // 2,001,920

// ---------------- workspace layout (bytes) ---------------- (same as r5)
#define WS_WALL    0           // Wall [128*128] f32 -> 65,536
#define WS_CBIAS   65536       // cbias [128] f32 -> 66,048
#define WS_P       66048       // p [N*8] f32 -> 3,266,048
#define WS_C       3266048     // c [N*128] bf16 -> 28,866,048
#define WS_RS      28866048    // row_start [N] i32 -> 29,266,048
#define WS_RE      29266048    // row_end [N] i32 -> 29,666,048
#define WS_CUR     29666048    // gcursor [NB] i32 -> 29,667,840 (padded)
#define WS_BUCK    29667840    // bucketed [NCAP] uint2 -> 45,683,200
#define WS_CSRCOL  45683200    // csr_col [NCAP] i32 -> 53,690,880
#define WS_CSRW    53690880    // csr_w [NCAP*2] u32 -> 69,706,240
// per-row cursor: aliased onto d_out's logits region (N floats, rewritten by k_agg)

static __device__ __forceinline__ unsigned short f2bf(float f) {
    union { float f; unsigned int u; } v; v.f = f;
    unsigned int u = v.u;
    return (unsigned short)((u + 0x7fffu + ((u >> 16) & 1u)) >> 16);  // RNE
}

// ---- fuse Wlin@Wconv -> Wall; cbias = blin@Wconv; init gcursor[b]=b*CAP ----
__global__ void k_fuse(const float* __restrict__ Wlin, const float* __restrict__ Wconv,
                       const float* __restrict__ blin, float* __restrict__ Wall,
                       float* __restrict__ cbias, int* __restrict__ gcursor) {
    int tid = blockIdx.x * 256 + threadIdx.x;
    if (tid < 16384) {
        int k = tid >> 12;
        int rem = tid & 4095;
        int f = rem >> 5;
        int q = rem & 31;
        float a = 0.f;
        for (int pp = 0; pp < 32; pp++)
            a += Wlin[(k * 128 + f) * 32 + pp] * Wconv[(k * 32 + pp) * 32 + q];
        Wall[f * 128 + k * 32 + q] = a;
    } else if (tid < 16512) {
        int i = tid - 16384;
        int k = i >> 5;
        int q = i & 31;
        float a = 0.f;
        for (int pp = 0; pp < 32; pp++)
            a += blin[k * 32 + pp] * Wconv[(k * 32 + pp) * 32 + q];
        cbias[k * 32 + q] = a;
    } else if (tid - 16512 < NB) {
        gcursor[tid - 16512] = (tid - 16512) * CAP;
    }
}

// ---- c[N,128] = bf16(x @ Wall + cbias)  AND  p[N,8] = x @ [aW1_lo | aW1_hi] ----
#define XS_LD 132
__global__ __launch_bounds__(256) void k_cgemm(const float* __restrict__ x,
                                               const float* __restrict__ Wall,
                                               const float* __restrict__ cbias,
                                               const float* __restrict__ aW1,
                                               unsigned short* __restrict__ c,
                                               float* __restrict__ p) {
    __shared__ float xs[64 * XS_LD];
    __shared__ float aT[8 * XS_LD];
    int t = threadIdx.x;
    int row0 = blockIdx.x * 64;

    for (int i = t; i < 1024; i += 256) {
        int j = i >> 7;
        int f = i & 127;
        float v = (j < 4) ? aW1[f * 4 + j] : aW1[512 + f * 4 + (j - 4)];
        aT[j * XS_LD + f] = v;
    }

    const float4* xg = (const float4*)(x + (size_t)row0 * 128);
    for (int i = 0; i < 8; i++) {
        int idx = i * 256 + t;
        int r = idx >> 5;
        int cc = idx & 31;
        float4 v = make_float4(0.f, 0.f, 0.f, 0.f);
        if (row0 + r < N_NODES) v = xg[idx];
        *(float4*)(xs + r * XS_LD + cc * 4) = v;
    }
    __syncthreads();

    int c0 = (t & 31) * 4;
    int r0 = (t >> 5) * 8;
    float acc[8][4] = {};

    for (int f4 = 0; f4 < 32; f4++) {
        float4 wf0 = *(const float4*)(Wall + (f4 * 4 + 0) * 128 + c0);
        float4 wf1 = *(const float4*)(Wall + (f4 * 4 + 1) * 128 + c0);
        float4 wf2 = *(const float4*)(Wall + (f4 * 4 + 2) * 128 + c0);
        float4 wf3 = *(const float4*)(Wall + (f4 * 4 + 3) * 128 + c0);
        for (int r = 0; r < 8; r++) {
            float4 xv = *(const float4*)(xs + (r0 + r) * XS_LD + f4 * 4);
            acc[r][0] += xv.x * wf0.x + xv.y * wf1.x + xv.z * wf2.x + xv.w * wf3.x;
            acc[r][1] += xv.x * wf0.y + xv.y * wf1.y + xv.z * wf2.y + xv.w * wf3.y;
            acc[r][2] += xv.x * wf0.z + xv.y * wf1.z + xv.z * wf2.z + xv.w * wf3.z;
            acc[r][3] += xv.x * wf0.w + xv.y * wf1.w + xv.z * wf2.w + xv.w * wf3.w;
        }
    }

    float4 cb = *(const float4*)(cbias + c0);
    for (int r = 0; r < 8; r++) {
        int row = row0 + r0 + r;
        if (row < N_NODES) {
            ushort4 o;
            o.x = f2bf(acc[r][0] + cb.x);
            o.y = f2bf(acc[r][1] + cb.y);
            o.z = f2bf(acc[r][2] + cb.z);
            o.w = f2bf(acc[r][3] + cb.w);
            *(ushort4*)(c + (size_t)row * 128 + c0) = o;
        }
    }

    int j = t & 7;
    const float* arow = aT + j * XS_LD;
    for (int pass = 0; pass < 2; pass++) {
        int r = (t >> 3) + pass * 32;
        const float* xrow = xs + r * XS_LD;
        float accp = 0.f;
        for (int f4 = 0; f4 < 32; f4++) {
            float4 xv = *(const float4*)(xrow + f4 * 4);
            float4 av = *(const float4*)(arow + f4 * 4);
            accp += xv.x * av.x + xv.y * av.y + xv.z * av.z + xv.w * av.w;
        }
        int row = row0 + r;
        if (row < N_NODES) p[(size_t)row * 8 + j] = accp;
    }
}

// ---- bucket scatter (512 thr): LDS-reorder tile by bucket, claim runs, copy out ----
__global__ __launch_bounds__(512) void k_bucket_scatter(const int* __restrict__ erow,
                                                        const int* __restrict__ ecol,
                                                        int* __restrict__ gcursor,
                                                        uint2* __restrict__ bucketed) {
    __shared__ int lcnt[NB];
    __shared__ int lstart[NB];
    __shared__ int lcur[NB];
    __shared__ int gbase[NB];
    __shared__ uint2 buf[TILE_E];
    int t = threadIdx.x;
    int tile = blockIdx.x;
    int base = tile * TILE_E;
    int cnt = N_EDGES - base; if (cnt > TILE_E) cnt = TILE_E;

    for (int i = t; i < NB; i += 512) lcnt[i] = 0;
    __syncthreads();

    int rows[TILE_E / 512], cols[TILE_E / 512];
    #pragma unroll
    for (int i = 0; i < TILE_E / 512; i++) {
        int e = base + i * 512 + t;
        if (e < N_EDGES) {
            rows[i] = erow[e];
            cols[i] = ecol[e];
            atomicAdd(&lcnt[rows[i] >> BSH], 1);
        } else rows[i] = -1;
    }
    __syncthreads();

    if (t < 64) {
        // wave 0: exclusive scan of lcnt -> lstart, lcur
        int carry = 0;
        for (int ck = 0; ck < (NB + 63) / 64; ck++) {
            int i = ck * 64 + t;
            int v = (i < NB) ? lcnt[i] : 0;
            int s = v;
            #pragma unroll
            for (int d = 1; d < 64; d <<= 1) {
                int u = __shfl_up(s, d);
                if (t >= d) s += u;
            }
            int excl = s - v + carry;
            if (i < NB) { lstart[i] = excl; lcur[i] = excl; }
            carry += __shfl(s, 63);
        }
    } else {
        // waves 1-7: claim global runs (overlapped with scan)
        for (int i = t - 64; i < NB; i += 448)
            gbase[i] = atomicAdd(&gcursor[i], lcnt[i]);
    }
    __syncthreads();

    #pragma unroll
    for (int i = 0; i < TILE_E / 512; i++) {
        if (rows[i] >= 0) {
            int b = rows[i] >> BSH;
            int pos = atomicAdd(&lcur[b], 1);
            buf[pos] = make_uint2((unsigned)rows[i], (unsigned)cols[i]);
        }
    }
    __syncthreads();

    for (int jj = t; jj < cnt; jj += 512) {
        uint2 pr = buf[jj];
        int b = (int)pr.x >> BSH;
        int gpos = gbase[b] + (jj - lstart[b]);
        bucketed[gpos] = pr;
    }
}

// ---- per-bucket row offsets (light): histogram + scan; init global row cursor ----
__global__ __launch_bounds__(256) void k_rowoffs(const uint2* __restrict__ bucketed,
                                                 const int* __restrict__ gcursor,
                                                 int* __restrict__ row_start,
                                                 int* __restrict__ row_end,
                                                 int* __restrict__ rowcur) {
    __shared__ int rh[256];
    __shared__ int wtot[4];
    int b = blockIdx.x;
    int t = threadIdx.x;
    int bstart = b * CAP;
    int bend = gcursor[b];
    int row0 = b << BSH;
    int nrows = N_NODES - row0; if (nrows > 256) nrows = 256;

    rh[t] = 0;
    __syncthreads();
    const int* brow = (const int*)bucketed;
    for (int i = bstart + t; i < bend; i += 256)
        atomicAdd(&rh[brow[(size_t)i * 2] - row0], 1);
    __syncthreads();
    int v = rh[t];
    int s = v;
    #pragma unroll
    for (int d = 1; d < 64; d <<= 1) {
        int u = __shfl_up(s, d);
        if ((t & 63) >= d) s += u;
    }
    if ((t & 63) == 63) wtot[t >> 6] = s;
    __syncthreads();
    int add = 0;
    for (int w = 0; w < (t >> 6); w++) add += wtot[w];
    int pos0 = bstart + (s - v + add);
    if (t < nrows) {
        row_start[row0 + t] = pos0;
        row_end[row0 + t] = pos0 + v;
        rowcur[row0 + t] = pos0;
    }
}

// ---- softmax + fine scatter: grid-stride over gapped bucket array ----
__global__ __launch_bounds__(256) void k_softmax_scatter(const uint2* __restrict__ bucketed,
                                                         const int* __restrict__ gcursor,
                                                         const float* __restrict__ p,
                                                         const float* __restrict__ aW2,
                                                         const float* __restrict__ ab1,
                                                         const float* __restrict__ ab2,
                                                         int* __restrict__ rowcur,
                                                         int* __restrict__ csr_col,
                                                         unsigned int* __restrict__ csr_w) {
    int i = blockIdx.x * 256 + threadIdx.x;
    if (i >= NCAP) return;
    int b = i / CAP;
    if (i >= gcursor[b]) return;    // gap region of this bucket

    uint2 pr = bucketed[i];
    int r = (int)pr.x;
    int cl = (int)pr.y;
    float4 pc = *(const float4*)(p + (size_t)cl * 8);
    float4 prr = *(const float4*)(p + (size_t)r * 8 + 4);
    float h0 = pc.x + prr.x + ab1[0];
    float h1 = pc.y + prr.y + ab1[1];
    float h2 = pc.z + prr.z + ab1[2];
    float h3 = pc.w + prr.w + ab1[3];
    float sc[4];
    #pragma unroll
    for (int jq = 0; jq < 4; jq++)
        sc[jq] = h0 * aW2[jq] + h1 * aW2[4 + jq] + h2 * aW2[8 + jq] + h3 * aW2[12 + jq] + ab2[jq];
    float m = fmaxf(fmaxf(sc[0], sc[1]), fmaxf(sc[2], sc[3]));
    float e0 = expf(sc[0] - m), e1 = expf(sc[1] - m), e2 = expf(sc[2] - m), e3 = expf(sc[3] - m);
    float inv = 1.f / (e0 + e1 + e2 + e3);
    unsigned int w01 = (unsigned int)f2bf(e0 * inv) | ((unsigned int)f2bf(e1 * inv) << 16);
    unsigned int w23 = (unsigned int)f2bf(e2 * inv) | ((unsigned int)f2bf(e3 * inv) << 16);
    int pos = atomicAdd(&rowcur[r], 1);
    csr_col[pos] = cl;
    uint2 wp; wp.x = w01; wp.y = w23;
    *(uint2*)(csr_w + (size_t)pos * 2) = wp;
}

// ---- aggregation: one wave per node; scalarized stream loads; bf16 gather ----
static __device__ __forceinline__ float bf_lo(unsigned int u) { return __uint_as_float(u << 16); }
static __device__ __forceinline__ float bf_hi(unsigned int u) { return __uint_as_float(u & 0xffff0000u); }

__global__ __launch_bounds__(256) void k_agg(const int* __restrict__ csr_col,
                                             const unsigned int* __restrict__ csr_w,
                                             const unsigned int* __restrict__ c4,
                                             const int* __restrict__ row_start,
                                             const int* __restrict__ row_end,
                                             const float* __restrict__ bch,
                                             const float* __restrict__ Wcls,
                                             const float* __restrict__ bcls,
                                             float* __restrict__ out) {
    int n = (blockIdx.x * 256 + threadIdx.x) >> 6;
    int lane = threadIdx.x & 63;
    if (n >= N_NODES) return;
    int ch = lane >> 4;
    int pair = ch >> 1;
    int wshl = (ch & 1) ? 0 : 16;
    int f0 = 2 * lane, f1 = 2 * lane + 1;

    // force wave-uniform loop bounds -> scalar loads in the loop body
    int start = __builtin_amdgcn_readfirstlane(row_start[n]);
    int end = __builtin_amdgcn_readfirstlane(row_end[n]);

    float acc0 = 0.f, acc1 = 0.f;
    int idx = start;
    for (; idx + 3 < end; idx += 4) {
        int col[4]; unsigned int wa[4], wb[4], u[4];
        #pragma unroll
        for (int q = 0; q < 4; q++) {
            col[q] = csr_col[idx + q];                    // s_load (uniform idx)
            wa[q] = csr_w[(size_t)(idx + q) * 2];         // s_load
            wb[q] = csr_w[(size_t)(idx + q) * 2 + 1];     // s_load
        }
        #pragma unroll
        for (int q = 0; q < 4; q++) u[q] = c4[(size_t)col[q] * 64 + lane];  // SGPR base + lane
        #pragma unroll
        for (int q = 0; q < 4; q++) {
            unsigned int wsel = pair ? wb[q] : wa[q];
            float w = __uint_as_float((wsel << wshl) & 0xffff0000u);
            acc0 += w * bf_lo(u[q]);
            acc1 += w * bf_hi(u[q]);
        }
    }
    for (; idx < end; idx++) {
        int col0 = csr_col[idx];
        unsigned int wa0 = csr_w[(size_t)idx * 2];
        unsigned int wb0 = csr_w[(size_t)idx * 2 + 1];
        unsigned int u0 = c4[(size_t)col0 * 64 + lane];
        unsigned int wsel = pair ? wb0 : wa0;
        float w = __uint_as_float((wsel << wshl) & 0xffff0000u);
        acc0 += w * bf_lo(u0);
        acc1 += w * bf_hi(u0);
    }

    float v0 = acc0 + bch[f0];
    float v1 = acc1 + bch[f1];

    float ss = v0 * v0 + v1 * v1;
    #pragma unroll
    for (int m = 1; m <= 8; m <<= 1) ss += __shfl_xor(ss, m);
    float inv = 1.f / fmaxf(sqrtf(ss), 1e-12f);
    v0 *= inv;
    v1 *= inv;

    *(float2*)(out + (size_t)n * 128 + f0) = make_float2(v0, v1);

    float pl = v0 * Wcls[f0] + v1 * Wcls[f1];
    #pragma unroll
    for (int m = 1; m <= 32; m <<= 1) pl += __shfl_xor(pl, m);
    if (lane == 0) out[(size_t)N_NODES * 128 + n] = pl + bcls[0];
}

extern "C" void kernel_launch(void* const* d_in, const int* in_sizes, int n_in,
                              void* d_out, int out_size, void* d_ws, size_t ws_size,
                              hipStream_t stream) {
    const float* x    = (const float*)d_in[0];
    const int*   erow = (const int*)d_in[1];
    const int*   ecol = (const int*)d_in[2];
    const float* aW1  = (const float*)d_in[3];
    const float* ab1  = (const float*)d_in[4];
    const float* aW2  = (const float*)d_in[5];
    const float* ab2  = (const float*)d_in[6];
    const float* Wlin = (const float*)d_in[7];
    const float* blin = (const float*)d_in[8];
    const float* Wconv= (const float*)d_in[9];
    const float* bch  = (const float*)d_in[10];
    const float* Wcls = (const float*)d_in[11];
    const float* bcls = (const float*)d_in[12];
    float* out = (float*)d_out;

    char* ws = (char*)d_ws;
    float*          Wall    = (float*)(ws + WS_WALL);
    float*          cbias   = (float*)(ws + WS_CBIAS);
    float*          p       = (float*)(ws + WS_P);
    unsigned short* c       = (unsigned short*)(ws + WS_C);
    int*            rstart  = (int*)(ws + WS_RS);
    int*            rend    = (int*)(ws + WS_RE);
    int*            gcursor = (int*)(ws + WS_CUR);
    uint2*          bucketed= (uint2*)(ws + WS_BUCK);
    int*            csr_col = (int*)(ws + WS_CSRCOL);
    unsigned int*   csr_w   = (unsigned int*)(ws + WS_CSRW);
    // per-row cursor aliased on d_out's logits region (rewritten by k_agg at the end)
    int*            rowcur  = (int*)(out + (size_t)N_NODES * 128);

    k_fuse<<<67, 256, 0, stream>>>(Wlin, Wconv, blin, Wall, cbias, gcursor);
    k_cgemm<<<(N_NODES + 63) / 64, 256, 0, stream>>>(x, Wall, cbias, aW1, c, p);
    k_bucket_scatter<<<T_TILES, 512, 0, stream>>>(erow, ecol, gcursor, bucketed);
    k_rowoffs<<<NB, 256, 0, stream>>>(bucketed, gcursor, rstart, rend, rowcur);
    k_softmax_scatter<<<(NCAP + 255) / 256, 256, 0, stream>>>(bucketed, gcursor, p, aW2,
                                                              ab1, ab2, rowcur, csr_col, csr_w);
    k_agg<<<(N_NODES * 64 + 255) / 256, 256, 0, stream>>>(csr_col, csr_w, (const unsigned int*)c,
                                                          rstart, rend, bch, Wcls, bcls, out);
}

// Round 7
// 292.545 us; speedup vs baseline: 1.1625x; 1.0986x over previous
//
#include <hip/hip_runtime.h>
#include <hip/hip_bf16.h>

#define N_NODES 100000
#define N_EDGES 1600000
#define NFEAT 128
#define PCD 32
#define KCH 4

#define TILE_E 4096
#define T_TILES 391            // ceil(N_EDGES / TILE_E)
#define BSH 8
#define NB 391                 // ceil(N_NODES / 256)
#define CAP 5120               // per-bucket capacity (mean 4096, +16 sigma)
#define NCAP (NB * CAP)        // 2,001,920

// ---------------- workspace layout (bytes) ----------------
#define WS_WALLB   0           // WallB packed bf16 [8][4][64][8] -> 32,768
#define WS_CBIAS   65536       // cbias [128] f32 -> 66,048
#define WS_P       66048       // p [N*8] f32 -> 3,266,048
#define WS_C       3266048     // c [N*128] bf16 -> 28,866,048
#define WS_RS      28866048    // row_start [N] i32 -> 29,266,048
#define WS_RE      29266048    // row_end [N] i32 -> 29,666,048
#define WS_CUR     29666048    // gcursor [NB] i32 -> 29,667,840 (padded)
#define WS_BUCK    29667840    // bucketed [NCAP] uint2 -> 45,683,200
#define WS_CSRCOL  45683200    // csr_col [NCAP] i32 -> 53,690,880
#define WS_CSRW    53690880    // csr_w [NCAP*2] u32 -> 69,706,240
// per-row cursor: aliased onto d_out's logits region (N floats, rewritten by k_agg)

typedef __attribute__((ext_vector_type(8))) short bfrag;   // 8 bf16 (4 VGPRs)
typedef __attribute__((ext_vector_type(4))) float ffrag;   // 4 f32 acc

static __device__ __forceinline__ unsigned short f2bf(float f) {
    union { float f; unsigned int u; } v; v.f = f;
    unsigned int u = v.u;
    return (unsigned short)((u + 0x7fffu + ((u >> 16) & 1u)) >> 16);  // RNE
}
static __device__ __forceinline__ float bf_lo(unsigned int u) { return __uint_as_float(u << 16); }
static __device__ __forceinline__ float bf_hi(unsigned int u) { return __uint_as_float(u & 0xffff0000u); }

// ---- fuse Wlin@Wconv -> WallB (packed B-frag bf16); cbias; init gcursor ----
__global__ void k_fuse(const float* __restrict__ Wlin, const float* __restrict__ Wconv,
                       const float* __restrict__ blin, unsigned short* __restrict__ WallB,
                       float* __restrict__ cbias, int* __restrict__ gcursor) {
    int tid = blockIdx.x * 256 + threadIdx.x;
    if (tid < 16384) {
        int k = tid >> 12;
        int rem = tid & 4095;
        int f = rem >> 5;          // k-index in GEMM (0..127)
        int q = rem & 31;
        float a = 0.f;
        for (int pp = 0; pp < 32; pp++)
            a += Wlin[(k * 128 + f) * 32 + pp] * Wconv[(k * 32 + pp) * 32 + q];
        int col = k * 32 + q;      // n-index (0..127)
        // packed B-fragment layout for mfma_f32_16x16x32_bf16:
        // lane = (klocal>>3)*16 + (col&15), j = klocal&7, klocal = f&31, kstep = f>>5
        int ntile = col >> 4, n15 = col & 15;
        int kstep = f >> 5, kl = f & 31;
        int lane = (kl >> 3) * 16 + n15;
        int j = kl & 7;
        WallB[(((ntile * 4 + kstep) * 64 + lane) << 3) + j] = f2bf(a);
    } else if (tid < 16512) {
        int i = tid - 16384;
        int k = i >> 5;
        int q = i & 31;
        float a = 0.f;
        for (int pp = 0; pp < 32; pp++)
            a += blin[k * 32 + pp] * Wconv[(k * 32 + pp) * 32 + q];
        cbias[k * 32 + q] = a;
    } else if (tid - 16512 < NB) {
        gcursor[tid - 16512] = (tid - 16512) * CAP;
    }
}

// ---- c[N,128] = bf16(x @ Wall + cbias) via MFMA;  p[N,8] = x @ aW1 (epilogue) ----
#define XLD 136   // bf16 elements per LDS row (16B-aligned frag reads)
__global__ __launch_bounds__(256) void k_cgemm(const float* __restrict__ x,
                                               const unsigned short* __restrict__ WallB,
                                               const float* __restrict__ cbias,
                                               const float* __restrict__ aW1,
                                               unsigned short* __restrict__ c,
                                               float* __restrict__ p) {
    __shared__ unsigned short xs[64 * XLD];   // 17,408 B (bf16 x-tile)
    __shared__ float aT[8 * 132];             // 4,224 B
    int t = threadIdx.x;
    int row0 = blockIdx.x * 64;
    int wv = t >> 6;
    int lane = t & 63;

    // stage aW1 transposed (fp32)
    for (int i = t; i < 1024; i += 256) {
        int j = i >> 7;
        int f = i & 127;
        float v = (j < 4) ? aW1[f * 4 + j] : aW1[512 + f * 4 + (j - 4)];
        aT[j * 132 + f] = v;
    }

    // stage 64 x-rows -> bf16 LDS
    const float4* xg = (const float4*)(x + (size_t)row0 * 128);
    for (int i = 0; i < 8; i++) {
        int idx = i * 256 + t;           // float4 index, 0..2047
        int r = idx >> 5;
        int cc = idx & 31;
        float4 v = make_float4(0.f, 0.f, 0.f, 0.f);
        if (row0 + r < N_NODES) v = xg[idx];
        ushort4 o;
        o.x = f2bf(v.x); o.y = f2bf(v.y); o.z = f2bf(v.z); o.w = f2bf(v.w);
        *(ushort4*)(xs + r * XLD + cc * 4) = o;
    }
    __syncthreads();

    // B fragments: wave wv owns cols [wv*32, wv*32+32) -> ntiles wv*2, wv*2+1
    bfrag B[2][4];
    #pragma unroll
    for (int nn = 0; nn < 2; nn++)
        #pragma unroll
        for (int ks = 0; ks < 4; ks++)
            B[nn][ks] = *(const bfrag*)(WallB + ((((wv * 2 + nn) * 4 + ks) * 64 + lane) << 3));

    ffrag acc[4][2];
    #pragma unroll
    for (int m = 0; m < 4; m++)
        #pragma unroll
        for (int nn = 0; nn < 2; nn++)
            acc[m][nn] = (ffrag){0.f, 0.f, 0.f, 0.f};

    int mrow = lane & 15;
    int koff = (lane >> 4) * 8;

    #pragma unroll
    for (int ks = 0; ks < 4; ks++) {
        bfrag A[4];
        #pragma unroll
        for (int m = 0; m < 4; m++)
            A[m] = *(const bfrag*)(xs + (m * 16 + mrow) * XLD + ks * 32 + koff);
        #pragma unroll
        for (int m = 0; m < 4; m++)
            #pragma unroll
            for (int nn = 0; nn < 2; nn++)
                acc[m][nn] = __builtin_amdgcn_mfma_f32_16x16x32_bf16(A[m], B[nn][ks], acc[m][nn], 0, 0, 0);
    }

    // epilogue: D[row = mtile*16 + quad*4 + r][col = wv*32 + nn*16 + (lane&15)]
    int quad = lane >> 4;
    int coln = lane & 15;
    #pragma unroll
    for (int nn = 0; nn < 2; nn++) {
        int col = wv * 32 + nn * 16 + coln;
        float cb = cbias[col];
        #pragma unroll
        for (int m = 0; m < 4; m++) {
            #pragma unroll
            for (int r = 0; r < 4; r++) {
                int row = row0 + m * 16 + quad * 4 + r;
                if (row < N_NODES)
                    c[(size_t)row * 128 + col] = f2bf(acc[m][nn][r] + cb);
            }
        }
    }

    // p epilogue (bf16 xs)
    int j = t & 7;
    const float* arow = aT + j * 132;
    for (int pass = 0; pass < 2; pass++) {
        int r = (t >> 3) + pass * 32;
        const unsigned int* xrow = (const unsigned int*)(xs + r * XLD);
        float accp = 0.f;
        #pragma unroll 8
        for (int f2 = 0; f2 < 64; f2++) {
            unsigned int u = xrow[f2];
            accp += bf_lo(u) * arow[2 * f2] + bf_hi(u) * arow[2 * f2 + 1];
        }
        int row = row0 + r;
        if (row < N_NODES) p[(size_t)row * 8 + j] = accp;
    }
}

// ---- bucket scatter (512 thr): LDS-reorder tile by bucket, claim runs, copy out ----
__global__ __launch_bounds__(512) void k_bucket_scatter(const int* __restrict__ erow,
                                                        const int* __restrict__ ecol,
                                                        int* __restrict__ gcursor,
                                                        uint2* __restrict__ bucketed) {
    __shared__ int lcnt[NB];
    __shared__ int lstart[NB];
    __shared__ int lcur[NB];
    __shared__ int gbase[NB];
    __shared__ uint2 buf[TILE_E];
    int t = threadIdx.x;
    int tile = blockIdx.x;
    int base = tile * TILE_E;
    int cnt = N_EDGES - base; if (cnt > TILE_E) cnt = TILE_E;

    for (int i = t; i < NB; i += 512) lcnt[i] = 0;
    __syncthreads();

    int rows[TILE_E / 512], cols[TILE_E / 512];
    #pragma unroll
    for (int i = 0; i < TILE_E / 512; i++) {
        int e = base + i * 512 + t;
        if (e < N_EDGES) {
            rows[i] = erow[e];
            cols[i] = ecol[e];
            atomicAdd(&lcnt[rows[i] >> BSH], 1);
        } else rows[i] = -1;
    }
    __syncthreads();

    if (t < 64) {
        int carry = 0;
        for (int ck = 0; ck < (NB + 63) / 64; ck++) {
            int i = ck * 64 + t;
            int v = (i < NB) ? lcnt[i] : 0;
            int s = v;
            #pragma unroll
            for (int d = 1; d < 64; d <<= 1) {
                int u = __shfl_up(s, d);
                if (t >= d) s += u;
            }
            int excl = s - v + carry;
            if (i < NB) { lstart[i] = excl; lcur[i] = excl; }
            carry += __shfl(s, 63);
        }
    } else {
        for (int i = t - 64; i < NB; i += 448)
            gbase[i] = atomicAdd(&gcursor[i], lcnt[i]);
    }
    __syncthreads();

    #pragma unroll
    for (int i = 0; i < TILE_E / 512; i++) {
        if (rows[i] >= 0) {
            int b = rows[i] >> BSH;
            int pos = atomicAdd(&lcur[b], 1);
            buf[pos] = make_uint2((unsigned)rows[i], (unsigned)cols[i]);
        }
    }
    __syncthreads();

    for (int jj = t; jj < cnt; jj += 512) {
        uint2 pr = buf[jj];
        int b = (int)pr.x >> BSH;
        int gpos = gbase[b] + (jj - lstart[b]);
        bucketed[gpos] = pr;
    }
}

// ---- per-bucket row offsets (light): histogram + scan; init global row cursor ----
__global__ __launch_bounds__(256) void k_rowoffs(const uint2* __restrict__ bucketed,
                                                 const int* __restrict__ gcursor,
                                                 int* __restrict__ row_start,
                                                 int* __restrict__ row_end,
                                                 int* __restrict__ rowcur) {
    __shared__ int rh[256];
    __shared__ int wtot[4];
    int b = blockIdx.x;
    int t = threadIdx.x;
    int bstart = b * CAP;
    int bend = gcursor[b];
    int row0 = b << BSH;
    int nrows = N_NODES - row0; if (nrows > 256) nrows = 256;

    rh[t] = 0;
    __syncthreads();
    const int* brow = (const int*)bucketed;
    for (int i = bstart + t; i < bend; i += 256)
        atomicAdd(&rh[brow[(size_t)i * 2] - row0], 1);
    __syncthreads();
    int v = rh[t];
    int s = v;
    #pragma unroll
    for (int d = 1; d < 64; d <<= 1) {
        int u = __shfl_up(s, d);
        if ((t & 63) >= d) s += u;
    }
    if ((t & 63) == 63) wtot[t >> 6] = s;
    __syncthreads();
    int add = 0;
    for (int w = 0; w < (t >> 6); w++) add += wtot[w];
    int pos0 = bstart + (s - v + add);
    if (t < nrows) {
        row_start[row0 + t] = pos0;
        row_end[row0 + t] = pos0 + v;
        rowcur[row0 + t] = pos0;
    }
}

// ---- softmax + fine scatter: grid-stride over gapped bucket array ----
__global__ __launch_bounds__(256) void k_softmax_scatter(const uint2* __restrict__ bucketed,
                                                         const int* __restrict__ gcursor,
                                                         const float* __restrict__ p,
                                                         const float* __restrict__ aW2,
                                                         const float* __restrict__ ab1,
                                                         const float* __restrict__ ab2,
                                                         int* __restrict__ rowcur,
                                                         int* __restrict__ csr_col,
                                                         unsigned int* __restrict__ csr_w) {
    int i = blockIdx.x * 256 + threadIdx.x;
    if (i >= NCAP) return;
    int b = i / CAP;
    if (i >= gcursor[b]) return;

    uint2 pr = bucketed[i];
    int r = (int)pr.x;
    int cl = (int)pr.y;
    float4 pc = *(const float4*)(p + (size_t)cl * 8);
    float4 prr = *(const float4*)(p + (size_t)r * 8 + 4);
    float h0 = pc.x + prr.x + ab1[0];
    float h1 = pc.y + prr.y + ab1[1];
    float h2 = pc.z + prr.z + ab1[2];
    float h3 = pc.w + prr.w + ab1[3];
    float sc[4];
    #pragma unroll
    for (int jq = 0; jq < 4; jq++)
        sc[jq] = h0 * aW2[jq] + h1 * aW2[4 + jq] + h2 * aW2[8 + jq] + h3 * aW2[12 + jq] + ab2[jq];
    float m = fmaxf(fmaxf(sc[0], sc[1]), fmaxf(sc[2], sc[3]));
    float e0 = expf(sc[0] - m), e1 = expf(sc[1] - m), e2 = expf(sc[2] - m), e3 = expf(sc[3] - m);
    float inv = 1.f / (e0 + e1 + e2 + e3);
    unsigned int w01 = (unsigned int)f2bf(e0 * inv) | ((unsigned int)f2bf(e1 * inv) << 16);
    unsigned int w23 = (unsigned int)f2bf(e2 * inv) | ((unsigned int)f2bf(e3 * inv) << 16);
    int pos = atomicAdd(&rowcur[r], 1);
    csr_col[pos] = cl;
    uint2 wp; wp.x = w01; wp.y = w23;
    *(uint2*)(csr_w + (size_t)pos * 2) = wp;
}

// ---- aggregation: one wave per node; scalarized stream loads; bf16 gather ----
__global__ __launch_bounds__(256) void k_agg(const int* __restrict__ csr_col,
                                             const unsigned int* __restrict__ csr_w,
                                             const unsigned int* __restrict__ c4,
                                             const int* __restrict__ row_start,
                                             const int* __restrict__ row_end,
                                             const float* __restrict__ bch,
                                             const float* __restrict__ Wcls,
                                             const float* __restrict__ bcls,
                                             float* __restrict__ out) {
    int n = (blockIdx.x * 256 + threadIdx.x) >> 6;
    int lane = threadIdx.x & 63;
    if (n >= N_NODES) return;
    int ch = lane >> 4;
    int pair = ch >> 1;
    int wshl = (ch & 1) ? 0 : 16;
    int f0 = 2 * lane, f1 = 2 * lane + 1;

    int start = __builtin_amdgcn_readfirstlane(row_start[n]);
    int end = __builtin_amdgcn_readfirstlane(row_end[n]);

    float acc0 = 0.f, acc1 = 0.f;
    int idx = start;
    for (; idx + 3 < end; idx += 4) {
        int col[4]; unsigned int wa[4], wb[4], u[4];
        #pragma unroll
        for (int q = 0; q < 4; q++) {
            col[q] = csr_col[idx + q];
            wa[q] = csr_w[(size_t)(idx + q) * 2];
            wb[q] = csr_w[(size_t)(idx + q) * 2 + 1];
        }
        #pragma unroll
        for (int q = 0; q < 4; q++) u[q] = c4[(size_t)col[q] * 64 + lane];
        #pragma unroll
        for (int q = 0; q < 4; q++) {
            unsigned int wsel = pair ? wb[q] : wa[q];
            float w = __uint_as_float((wsel << wshl) & 0xffff0000u);
            acc0 += w * bf_lo(u[q]);
            acc1 += w * bf_hi(u[q]);
        }
    }
    for (; idx < end; idx++) {
        int col0 = csr_col[idx];
        unsigned int wa0 = csr_w[(size_t)idx * 2];
        unsigned int wb0 = csr_w[(size_t)idx * 2 + 1];
        unsigned int u0 = c4[(size_t)col0 * 64 + lane];
        unsigned int wsel = pair ? wb0 : wa0;
        float w = __uint_as_float((wsel << wshl) & 0xffff0000u);
        acc0 += w * bf_lo(u0);
        acc1 += w * bf_hi(u0);
    }

    float v0 = acc0 + bch[f0];
    float v1 = acc1 + bch[f1];

    float ss = v0 * v0 + v1 * v1;
    #pragma unroll
    for (int m = 1; m <= 8; m <<= 1) ss += __shfl_xor(ss, m);
    float inv = 1.f / fmaxf(sqrtf(ss), 1e-12f);
    v0 *= inv;
    v1 *= inv;

    *(float2*)(out + (size_t)n * 128 + f0) = make_float2(v0, v1);

    float pl = v0 * Wcls[f0] + v1 * Wcls[f1];
    #pragma unroll
    for (int m = 1; m <= 32; m <<= 1) pl += __shfl_xor(pl, m);
    if (lane == 0) out[(size_t)N_NODES * 128 + n] = pl + bcls[0];
}

extern "C" void kernel_launch(void* const* d_in, const int* in_sizes, int n_in,
                              void* d_out, int out_size, void* d_ws, size_t ws_size,
                              hipStream_t stream) {
    const float* x    = (const float*)d_in[0];
    const int*   erow = (const int*)d_in[1];
    const int*   ecol = (const int*)d_in[2];
    const float* aW1  = (const float*)d_in[3];
    const float* ab1  = (const float*)d_in[4];
    const float* aW2  = (const float*)d_in[5];
    const float* ab2  = (const float*)d_in[6];
    const float* Wlin = (const float*)d_in[7];
    const float* blin = (const float*)d_in[8];
    const float* Wconv= (const float*)d_in[9];
    const float* bch  = (const float*)d_in[10];
    const float* Wcls = (const float*)d_in[11];
    const float* bcls = (const float*)d_in[12];
    float* out = (float*)d_out;

    char* ws = (char*)d_ws;
    unsigned short* WallB   = (unsigned short*)(ws + WS_WALLB);
    float*          cbias   = (float*)(ws + WS_CBIAS);
    float*          p       = (float*)(ws + WS_P);
    unsigned short* c       = (unsigned short*)(ws + WS_C);
    int*            rstart  = (int*)(ws + WS_RS);
    int*            rend    = (int*)(ws + WS_RE);
    int*            gcursor = (int*)(ws + WS_CUR);
    uint2*          bucketed= (uint2*)(ws + WS_BUCK);
    int*            csr_col = (int*)(ws + WS_CSRCOL);
    unsigned int*   csr_w   = (unsigned int*)(ws + WS_CSRW);
    int*            rowcur  = (int*)(out + (size_t)N_NODES * 128);

    k_fuse<<<67, 256, 0, stream>>>(Wlin, Wconv, blin, WallB, cbias, gcursor);
    k_cgemm<<<(N_NODES + 63) / 64, 256, 0, stream>>>(x, WallB, cbias, aW1, c, p);
    k_bucket_scatter<<<T_TILES, 512, 0, stream>>>(erow, ecol, gcursor, bucketed);
    k_rowoffs<<<NB, 256, 0, stream>>>(bucketed, gcursor, rstart, rend, rowcur);
    k_softmax_scatter<<<(NCAP + 255) / 256, 256, 0, stream>>>(bucketed, gcursor, p, aW2,
                                                              ab1, ab2, rowcur, csr_col, csr_w);
    k_agg<<<(N_NODES * 64 + 255) / 256, 256, 0, stream>>>(csr_col, csr_w, (const unsigned int*)c,
                                                          rstart, rend, bch, Wcls, bcls, out);
}